// Round 3
// baseline (17951.224 us; speedup 1.0000x reference)
//
#include <hip/hip_runtime.h>
#include <hip/hip_bf16.h>
#include <math.h>

#define Bz 64
#define Sz 256
#define Dz 256
#define Hz 512
#define FH 2048   // 4H
#define OH 1024   // 2H
#define Tz 48
#define EPSV 1e-5f

typedef __hip_bfloat16 bf16;
typedef __attribute__((ext_vector_type(8))) short short8;
typedef __attribute__((ext_vector_type(4))) float floatx4;

__device__ __forceinline__ float sigf(float x){ return 1.f/(1.f+expf(-x)); }
__device__ __forceinline__ float b2f(bf16 v){ return __bfloat162float(v); }

__device__ __forceinline__ void load4f(const bf16* p, float v[4]) {
  ushort4 t = *(const ushort4*)p;
  v[0] = __uint_as_float(((unsigned)t.x) << 16);
  v[1] = __uint_as_float(((unsigned)t.y) << 16);
  v[2] = __uint_as_float(((unsigned)t.z) << 16);
  v[3] = __uint_as_float(((unsigned)t.w) << 16);
}
__device__ __forceinline__ void storev(float* p, float v){ *p = v; }
__device__ __forceinline__ void storev(bf16* p, float v){ *p = __float2bfloat16(v); }

// ---------- fp32 -> bf16 cast ----------
__global__ __launch_bounds__(256) void castf2b(const float* __restrict__ in, bf16* __restrict__ out, int n)
{
  int i = (blockIdx.x*256 + threadIdx.x)*4;
  if (i >= n) return;
  float4 v = *(const float4*)(in + i);
  bf16 tmp[4];
  tmp[0] = __float2bfloat16(v.x); tmp[1] = __float2bfloat16(v.y);
  tmp[2] = __float2bfloat16(v.z); tmp[3] = __float2bfloat16(v.w);
  *(uint2*)(out + i) = *(const uint2*)tmp;
}

__global__ __launch_bounds__(256) void bnprep_k(const float* __restrict__ gamma, const float* __restrict__ beta,
  const float* __restrict__ mean, const float* __restrict__ var,
  float* __restrict__ scale, float* __restrict__ shift)
{
  int i = blockIdx.x*256 + threadIdx.x;
  if (i >= OH) return;
  float s = gamma[i]*rsqrtf(var[i]+EPSV);
  scale[i] = s; shift[i] = beta[i] - mean[i]*s;
}

// ---------- MFMA bf16 GEMM: C = A(MxK) * W(NxK)^T + b1 + b2, opt relu ----------
// 128x128 block tile, BK=32, 4 waves each 64x64. M,N %128==0, K %32==0.
template<typename TC>
__global__ __launch_bounds__(256) void gemm_mfma(
  const bf16* __restrict__ A, const bf16* __restrict__ W,
  const float* __restrict__ b1, const float* __restrict__ b2,
  TC* __restrict__ Cv, int M, int N, int K, int relu)
{
  __shared__ bf16 As[128][40];   // 80B rows: 16B-aligned frag reads, conflict-light
  __shared__ bf16 Bs[128][40];
  int tid = threadIdx.x;
  int wave = tid>>6, lane = tid&63, l15 = lane&15, quad = lane>>4;
  int m0 = blockIdx.y*128, n0 = blockIdx.x*128;
  int wm = (wave>>1)*64, wn = (wave&1)*64;
  int srow = tid>>1, scw = (tid&1)*16;
  const bf16* Ap = A + (size_t)(m0+srow)*K + scw;
  const bf16* Wp = W + (size_t)(n0+srow)*K + scw;
  floatx4 zero = {0.f,0.f,0.f,0.f};
  floatx4 acc[4][4];
  #pragma unroll
  for (int i=0;i<4;i++)
    #pragma unroll
    for (int j=0;j<4;j++) acc[i][j] = zero;

  for (int k0 = 0; k0 < K; k0 += 32) {
    float4 a0 = *(const float4*)Ap, a1 = *(const float4*)(Ap+8);
    float4 w0 = *(const float4*)Wp, w1 = *(const float4*)(Wp+8);
    Ap += 32; Wp += 32;
    __syncthreads();
    *(float4*)&As[srow][scw]   = a0; *(float4*)&As[srow][scw+8] = a1;
    *(float4*)&Bs[srow][scw]   = w0; *(float4*)&Bs[srow][scw+8] = w1;
    __syncthreads();
    short8 af[4], bfv[4];
    #pragma unroll
    for (int mi=0;mi<4;mi++) af[mi]  = *(const short8*)&As[wm+mi*16+l15][quad*8];
    #pragma unroll
    for (int ni=0;ni<4;ni++) bfv[ni] = *(const short8*)&Bs[wn+ni*16+l15][quad*8];
    #pragma unroll
    for (int mi=0;mi<4;mi++)
      #pragma unroll
      for (int ni=0;ni<4;ni++)
        acc[mi][ni] = __builtin_amdgcn_mfma_f32_16x16x32_bf16(af[mi], bfv[ni], acc[mi][ni], 0,0,0);
  }
  #pragma unroll
  for (int mi=0;mi<4;mi++){
    #pragma unroll
    for (int ni=0;ni<4;ni++){
      int n = n0 + wn + ni*16 + l15;
      float bb = (b1 ? b1[n] : 0.f) + (b2 ? b2[n] : 0.f);
      #pragma unroll
      for (int r=0;r<4;r++){
        int m = m0 + wm + mi*16 + quad*4 + r;
        float v = acc[mi][ni][r] + bb;
        if (relu) v = fmaxf(v, 0.f);
        storev(&Cv[(size_t)m*N + n], v);
      }
    }
  }
}

// ---------- naive fp32 GEMM (kept for fc3, N=48) ----------
__global__ __launch_bounds__(256) void gemm_nt_small(
  const bf16* __restrict__ A, const float* __restrict__ W,
  const float* __restrict__ b1, float* __restrict__ Cv, int M, int N, int K)
{
  __shared__ float As[8][128];
  __shared__ float Ws[8][128];
  int tid = threadIdx.x;
  int tx = tid & 15, ty = tid >> 4;
  int m0 = blockIdx.y * 128, n0 = blockIdx.x * 128;
  int sr = tid >> 1;
  int sk = (tid & 1) * 4;
  const bf16* Ap = A + (size_t)(m0 + sr) * K + sk;
  bool wok = (n0 + sr) < N;
  const float* Wp = W + (size_t)(wok ? (n0 + sr) : 0) * K + sk;
  float acc[8][8] = {};
  for (int k0 = 0; k0 < K; k0 += 8) {
    float av[4], wv[4];
    load4f(Ap, av);
    if (wok) { float4 t = *(const float4*)Wp; wv[0]=t.x; wv[1]=t.y; wv[2]=t.z; wv[3]=t.w; }
    else { wv[0]=wv[1]=wv[2]=wv[3]=0.f; }
    Ap += 8; Wp += 8;
    __syncthreads();
    As[sk+0][sr]=av[0]; As[sk+1][sr]=av[1]; As[sk+2][sr]=av[2]; As[sk+3][sr]=av[3];
    Ws[sk+0][sr]=wv[0]; Ws[sk+1][sr]=wv[1]; Ws[sk+2][sr]=wv[2]; Ws[sk+3][sr]=wv[3];
    __syncthreads();
    #pragma unroll
    for (int kk = 0; kk < 8; kk++) {
      float a[8], w[8];
      *(float4*)&a[0] = *(const float4*)&As[kk][ty*8];
      *(float4*)&a[4] = *(const float4*)&As[kk][ty*8+4];
      *(float4*)&w[0] = *(const float4*)&Ws[kk][tx*8];
      *(float4*)&w[4] = *(const float4*)&Ws[kk][tx*8+4];
      #pragma unroll
      for (int i=0;i<8;i++)
        #pragma unroll
        for (int j=0;j<8;j++) acc[i][j] += a[i]*w[j];
    }
  }
  #pragma unroll
  for (int i=0;i<8;i++){
    int m = m0 + ty*8 + i;
    #pragma unroll
    for (int j=0;j<8;j++){
      int n = n0 + tx*8 + j;
      if (n < N) Cv[(size_t)m*N + n] = acc[i][j] + b1[n];
    }
  }
}

// ---------- MFMA LSTM step: both dirs, 16 blocks (dir x 8 jtiles of 64) ----------
// Wave w: batches w*16..w*16+15, all 4 gates for this jtile (16 n-tiles of 16).
// Gates land in-register per lane -> nonlinearity without LDS round-trip.
__global__ __launch_bounds__(256) void lstm_step_mfma(
  const bf16* __restrict__ preF, const bf16* __restrict__ preB,
  const bf16* __restrict__ WF, const bf16* __restrict__ WB,     // Whh bf16 (2048 x 512) row-major
  const bf16* __restrict__ hFin, bf16* __restrict__ hFout, float* __restrict__ cF,
  const bf16* __restrict__ hBin, bf16* __restrict__ hBout, float* __restrict__ cB,
  bf16* __restrict__ xout, const float* __restrict__ bnscale, const float* __restrict__ bnshift,
  int t)
{
  __shared__ bf16 hs[64][72];     // [batch][k]  144B rows -> 2-way max on frag reads
  __shared__ bf16 Ws[256][72];    // [gate*64 + jloc][k]
  int blk = blockIdx.x;
  int dir = blk & 1;
  int j0 = (blk >> 1) * 64;
  const bf16* pre = dir ? preB : preF;
  const bf16* Wt  = dir ? WB : WF;
  const bf16* hin = dir ? hBin : hFin;
  bf16* hout = dir ? hBout : hFout;
  float* cst  = dir ? cB : cF;
  int colOff = dir ? Hz : 0;
  int tcur = dir ? (Sz-1 - t) : t;
  int tid = threadIdx.x;
  int wave = tid>>6, lane = tid&63, l15 = lane&15, quad = lane>>4;

  floatx4 zero = {0.f,0.f,0.f,0.f};
  floatx4 acc[16];
  #pragma unroll
  for (int i=0;i<16;i++) acc[i] = zero;

  int srow = tid>>2;            // 0..63
  int scw  = (tid&3)*16;        // element offset in 64-wide k window
  const bf16* hgp = hin + (size_t)srow*Hz + scw;
  size_t wbase = (size_t)(j0 + srow)*Hz + scw;

  for (int k0 = 0; k0 < Hz; k0 += 64) {
    float4 h0 = *(const float4*)hgp, h1 = *(const float4*)(hgp+8);
    hgp += 64;
    float4 wv[4][2];
    #pragma unroll
    for (int q=0;q<4;q++){
      const bf16* wp = Wt + (size_t)q*512*Hz + wbase + k0;
      wv[q][0] = *(const float4*)wp;
      wv[q][1] = *(const float4*)(wp+8);
    }
    __syncthreads();
    *(float4*)&hs[srow][scw]   = h0; *(float4*)&hs[srow][scw+8] = h1;
    #pragma unroll
    for (int q=0;q<4;q++){
      *(float4*)&Ws[q*64 + srow][scw]   = wv[q][0];
      *(float4*)&Ws[q*64 + srow][scw+8] = wv[q][1];
    }
    __syncthreads();
    #pragma unroll
    for (int kw=0; kw<2; kw++){
      short8 af = *(const short8*)&hs[wave*16 + l15][kw*32 + quad*8];
      #pragma unroll
      for (int ni=0; ni<16; ni++){
        short8 bfv = *(const short8*)&Ws[ni*16 + l15][kw*32 + quad*8];
        acc[ni] = __builtin_amdgcn_mfma_f32_16x16x32_bf16(af, bfv, acc[ni], 0,0,0);
      }
    }
  }

  // epilogue: acc[g*4+jb][r] = gate g, batch wave*16+quad*4+r, col j0+jb*16+l15
  #pragma unroll
  for (int r=0;r<4;r++){
    int b = wave*16 + quad*4 + r;
    const bf16* pb = pre + ((size_t)b*Sz + tcur)*FH;
    #pragma unroll
    for (int jb=0;jb<4;jb++){
      int j = j0 + jb*16 + l15;
      float gi = acc[jb][r]      + b2f(pb[j]);
      float gf = acc[4+jb][r]    + b2f(pb[Hz + j]);
      float gg = acc[8+jb][r]    + b2f(pb[2*Hz + j]);
      float go = acc[12+jb][r]   + b2f(pb[3*Hz + j]);
      size_t ci = (size_t)b*Hz + j;
      float c = sigf(gf)*cst[ci] + sigf(gi)*tanhf(gg);
      float h = sigf(go)*tanhf(c);
      cst[ci] = c;
      hout[ci] = __float2bfloat16(h);
      float xv = h;
      if (bnscale) xv = h*bnscale[colOff + j] + bnshift[colOff + j];
      xout[((size_t)b*Sz + tcur)*OH + colOff + j] = __float2bfloat16(xv);
    }
  }
}

// ---------- CRF ----------
__global__ __launch_bounds__(64) void crf_k(const float* __restrict__ em, const int* __restrict__ tags,
  const float* __restrict__ start, const float* __restrict__ endv, const float* __restrict__ trans,
  float* __restrict__ result)
{
  __shared__ float tr[Tz*Tz];
  __shared__ float alpha[2][Tz];
  int b = blockIdx.x, tid = threadIdx.x;
  for (int i = tid; i < Tz*Tz; i += 64) tr[i] = trans[i];
  float np = 0.f;
  for (int t = tid; t < Sz; t += 64) {
    int tg = tags[b*Sz + t];
    np += em[((size_t)b*Sz + t)*Tz + tg];
    if (t+1 < Sz) np += trans[tg*Tz + tags[b*Sz + t + 1]];
  }
  #pragma unroll
  for (int off = 32; off; off >>= 1) np += __shfl_down(np, off);
  float num = 0.f;
  if (tid == 0) num = np + start[tags[b*Sz]] + endv[tags[b*Sz + Sz-1]];
  if (tid < Tz) alpha[0][tid] = start[tid] + em[((size_t)b*Sz)*Tz + tid];
  __syncthreads();
  int cur = 0;
  for (int t = 1; t < Sz; t++) {
    if (tid < Tz) {
      float m = -1e30f;
      for (int i = 0; i < Tz; i++) m = fmaxf(m, alpha[cur][i] + tr[i*Tz + tid]);
      float sum = 0.f;
      for (int i = 0; i < Tz; i++) sum += expf(alpha[cur][i] + tr[i*Tz + tid] - m);
      alpha[1-cur][tid] = m + logf(sum) + em[((size_t)b*Sz + t)*Tz + tid];
    }
    cur ^= 1;
    __syncthreads();
  }
  float a = (tid < Tz) ? alpha[cur][tid] + endv[tid] : -1e30f;
  float m = a;
  #pragma unroll
  for (int off = 32; off; off >>= 1) m = fmaxf(m, __shfl_down(m, off));
  m = __shfl(m, 0);
  float e = (tid < Tz) ? expf(a - m) : 0.f;
  #pragma unroll
  for (int off = 32; off; off >>= 1) e += __shfl_down(e, off);
  if (tid == 0) result[b] = num - (m + logf(e));
}

__global__ __launch_bounds__(64) void finalize_k(const float* __restrict__ result, float* __restrict__ outp)
{
  float v = result[threadIdx.x];
  #pragma unroll
  for (int off = 32; off; off >>= 1) v += __shfl_down(v, off);
  if (threadIdx.x == 0) outp[0] = -(v * (1.f/64.f));
}

extern "C" void kernel_launch(void* const* d_in, const int* in_sizes, int n_in,
                              void* d_out, int out_size, void* d_ws, size_t ws_size,
                              hipStream_t stream)
{
  (void)in_sizes; (void)n_in; (void)out_size; (void)ws_size;
  const float* inputs = (const float*)d_in[0];
  const int*   tags   = (const int*)d_in[1];
  const float* Wih[2][2] = {{(const float*)d_in[2],  (const float*)d_in[6]},
                            {(const float*)d_in[10], (const float*)d_in[14]}};
  const float* Whh[2][2] = {{(const float*)d_in[3],  (const float*)d_in[7]},
                            {(const float*)d_in[11], (const float*)d_in[15]}};
  const float* bih[2][2] = {{(const float*)d_in[4],  (const float*)d_in[8]},
                            {(const float*)d_in[12], (const float*)d_in[16]}};
  const float* bhh[2][2] = {{(const float*)d_in[5],  (const float*)d_in[9]},
                            {(const float*)d_in[13], (const float*)d_in[17]}};
  const float* bn_gamma = (const float*)d_in[18];
  const float* bn_beta  = (const float*)d_in[19];
  const float* bn_mean  = (const float*)d_in[20];
  const float* bn_var   = (const float*)d_in[21];
  const float* fc1_w = (const float*)d_in[22];
  const float* fc1_b = (const float*)d_in[23];
  const float* fc2_w = (const float*)d_in[24];
  const float* fc2_b = (const float*)d_in[25];
  const float* fc3_w = (const float*)d_in[26];
  const float* fc3_b = (const float*)d_in[27];
  const float* crf_start = (const float*)d_in[28];
  const float* crf_end   = (const float*)d_in[29];
  const float* crf_trans = (const float*)d_in[30];

  const size_t M = (size_t)Bz*Sz;   // 16384
  char* p = (char*)d_ws;
  auto alloc = [&](size_t bytes) { char* r = p; p += (bytes + 255) & ~(size_t)255; return r; };
  bf16*  preF = (bf16*) alloc(M*FH*sizeof(bf16));            // 64 MB
  bf16*  preB = (bf16*) alloc(M*FH*sizeof(bf16));            // 64 MB
  bf16*  xbuf = (bf16*) alloc(M*OH*sizeof(bf16));            // 32 MB (x0 -> x1 -> fc1 input)
  bf16*  inbf = (bf16*) alloc(M*Dz*sizeof(bf16));            // 8 MB (inputs bf16; em overlays later)
  bf16*  WihA = (bf16*) alloc((size_t)FH*OH*sizeof(bf16));   // 4 MB (layer-dependent reuse)
  bf16*  WihB = (bf16*) alloc((size_t)FH*OH*sizeof(bf16));   // 4 MB
  bf16*  WhhA = (bf16*) alloc((size_t)FH*Hz*sizeof(bf16));   // 2 MB
  bf16*  WhhB = (bf16*) alloc((size_t)FH*Hz*sizeof(bf16));   // 2 MB
  bf16*  fc1wb = (bf16*)alloc((size_t)Hz*OH*sizeof(bf16));   // 1 MB
  bf16*  fc2wb = (bf16*)alloc((size_t)256*Hz*sizeof(bf16));  // 0.25 MB
  char*  stc  = alloc(4*(size_t)Bz*Hz*sizeof(bf16) + 2*(size_t)Bz*Hz*sizeof(float)); // 512 KB
  float* bnscale = (float*)alloc(OH*sizeof(float));
  float* bnshift = (float*)alloc(OH*sizeof(float));
  float* result  = (float*)alloc(Bz*sizeof(float));
  float* em   = (float*)inbf;                                // overlay: 3 MB <= 8 MB
  bf16* fc1o = (bf16*)preF;                                  // overlay after recurrence
  bf16* fc2o = (bf16*)preB;

  bf16* hF0 = (bf16*)stc;
  bf16* hF1 = hF0 + (size_t)Bz*Hz;
  bf16* hB0 = hF1 + (size_t)Bz*Hz;
  bf16* hB1 = hB0 + (size_t)Bz*Hz;
  float* cF = (float*)(hB1 + (size_t)Bz*Hz);
  float* cB = cF + (size_t)Bz*Hz;
  size_t stBytes = 4*(size_t)Bz*Hz*sizeof(bf16) + 2*(size_t)Bz*Hz*sizeof(float);

  dim3 tb(256);
  auto cast = [&](const float* src, bf16* dst, size_t n){
    castf2b<<<(n/4 + 255)/256, tb, 0, stream>>>(src, dst, (int)n);
  };

  // upfront casts
  cast(inputs, inbf, M*Dz);
  cast(Wih[0][0], WihA, (size_t)FH*Dz);
  cast(Wih[0][1], WihB, (size_t)FH*Dz);
  cast(Whh[0][0], WhhA, (size_t)FH*Hz);
  cast(Whh[0][1], WhhB, (size_t)FH*Hz);
  cast(fc1_w, fc1wb, (size_t)Hz*OH);
  cast(fc2_w, fc2wb, (size_t)256*Hz);
  bnprep_k<<<OH/256, tb, 0, stream>>>(bn_gamma, bn_beta, bn_mean, bn_var, bnscale, bnshift);

  // ---- layer 0 ----
  hipMemsetAsync(stc, 0, stBytes, stream);
  gemm_mfma<bf16><<<dim3(FH/128, M/128), tb, 0, stream>>>(inbf, WihA, bih[0][0], bhh[0][0], preF, M, FH, Dz, 0);
  gemm_mfma<bf16><<<dim3(FH/128, M/128), tb, 0, stream>>>(inbf, WihB, bih[0][1], bhh[0][1], preB, M, FH, Dz, 0);
  for (int t = 0; t < Sz; t++) {
    const bf16* hFi = (t & 1) ? hF1 : hF0; bf16* hFo = (t & 1) ? hF0 : hF1;
    const bf16* hBi = (t & 1) ? hB1 : hB0; bf16* hBo = (t & 1) ? hB0 : hB1;
    lstm_step_mfma<<<16, tb, 0, stream>>>(preF, preB, WhhA, WhhB, hFi, hFo, cF, hBi, hBo, cB,
                                          xbuf, nullptr, nullptr, t);
  }
  // ---- layer 1 ----
  cast(Wih[1][0], WihA, (size_t)FH*OH);
  cast(Wih[1][1], WihB, (size_t)FH*OH);
  cast(Whh[1][0], WhhA, (size_t)FH*Hz);
  cast(Whh[1][1], WhhB, (size_t)FH*Hz);
  hipMemsetAsync(stc, 0, stBytes, stream);
  gemm_mfma<bf16><<<dim3(FH/128, M/128), tb, 0, stream>>>(xbuf, WihA, bih[1][0], bhh[1][0], preF, M, FH, OH, 0);
  gemm_mfma<bf16><<<dim3(FH/128, M/128), tb, 0, stream>>>(xbuf, WihB, bih[1][1], bhh[1][1], preB, M, FH, OH, 0);
  for (int t = 0; t < Sz; t++) {
    const bf16* hFi = (t & 1) ? hF1 : hF0; bf16* hFo = (t & 1) ? hF0 : hF1;
    const bf16* hBi = (t & 1) ? hB1 : hB0; bf16* hBo = (t & 1) ? hB0 : hB1;
    lstm_step_mfma<<<16, tb, 0, stream>>>(preF, preB, WhhA, WhhB, hFi, hFo, cF, hBi, hBo, cB,
                                          xbuf, bnscale, bnshift, t);   // BN folded into x-write
  }
  // ---- head ----
  gemm_mfma<bf16><<<dim3(Hz/128, M/128), tb, 0, stream>>>(xbuf, fc1wb, fc1_b, nullptr, fc1o, M, Hz, OH, 1);
  gemm_mfma<bf16><<<dim3(256/128, M/128), tb, 0, stream>>>(fc1o, fc2wb, fc2_b, nullptr, fc2o, M, 256, Hz, 1);
  gemm_nt_small<<<dim3(1, M/128), tb, 0, stream>>>(fc2o, fc3_w, fc3_b, em, M, Tz, 256);
  crf_k<<<Bz, 64, 0, stream>>>(em, tags, crf_start, crf_end, crf_trans, result);
  finalize_k<<<1, 64, 0, stream>>>(result, (float*)d_out);
}

// Round 4
// 5337.540 us; speedup vs baseline: 3.3632x; 3.3632x over previous
//
#include <hip/hip_runtime.h>
#include <hip/hip_bf16.h>
#include <math.h>

#define Bz 64
#define Sz 256
#define Dz 256
#define Hz 512
#define FH 2048   // 4H
#define OH 1024   // 2H
#define Tz 48
#define EPSV 1e-5f
#define LOG2E 1.44269504f

typedef __hip_bfloat16 bf16;
typedef __attribute__((ext_vector_type(8))) short short8;
typedef __attribute__((ext_vector_type(4))) float floatx4;

__device__ __forceinline__ float b2f(bf16 v){ return __bfloat162float(v); }
// fast sigmoid/tanh on v_exp_f32 / v_rcp_f32
__device__ __forceinline__ float fsig(float x){
  float e = __builtin_amdgcn_exp2f(-x*LOG2E);
  return __builtin_amdgcn_rcpf(1.f + e);
}
__device__ __forceinline__ float ftanh(float x){
  float e = __builtin_amdgcn_exp2f(x*(2.f*LOG2E));
  return 1.f - 2.f*__builtin_amdgcn_rcpf(e + 1.f);
}

__device__ __forceinline__ void load4f(const bf16* p, float v[4]) {
  ushort4 t = *(const ushort4*)p;
  v[0] = __uint_as_float(((unsigned)t.x) << 16);
  v[1] = __uint_as_float(((unsigned)t.y) << 16);
  v[2] = __uint_as_float(((unsigned)t.z) << 16);
  v[3] = __uint_as_float(((unsigned)t.w) << 16);
}
__device__ __forceinline__ void storev(float* p, float v){ *p = v; }
__device__ __forceinline__ void storev(bf16* p, float v){ *p = __float2bfloat16(v); }

// ---------- fp32 -> bf16 cast ----------
__global__ __launch_bounds__(256) void castf2b(const float* __restrict__ in, bf16* __restrict__ out, int n)
{
  int i = (blockIdx.x*256 + threadIdx.x)*4;
  if (i >= n) return;
  float4 v = *(const float4*)(in + i);
  bf16 tmp[4];
  tmp[0] = __float2bfloat16(v.x); tmp[1] = __float2bfloat16(v.y);
  tmp[2] = __float2bfloat16(v.z); tmp[3] = __float2bfloat16(v.w);
  *(uint2*)(out + i) = *(const uint2*)tmp;
}

__global__ __launch_bounds__(256) void bnprep_k(const float* __restrict__ gamma, const float* __restrict__ beta,
  const float* __restrict__ mean, const float* __restrict__ var,
  float* __restrict__ scale, float* __restrict__ shift)
{
  int i = blockIdx.x*256 + threadIdx.x;
  if (i >= OH) return;
  float s = gamma[i]*rsqrtf(var[i]+EPSV);
  scale[i] = s; shift[i] = beta[i] - mean[i]*s;
}

// ---------- MFMA bf16 GEMM: C = A(MxK) * W(NxK)^T + b1 + b2, opt relu ----------
template<typename TC>
__global__ __launch_bounds__(256) void gemm_mfma(
  const bf16* __restrict__ A, const bf16* __restrict__ W,
  const float* __restrict__ b1, const float* __restrict__ b2,
  TC* __restrict__ Cv, int M, int N, int K, int relu)
{
  __shared__ bf16 As[128][40];
  __shared__ bf16 Bs[128][40];
  int tid = threadIdx.x;
  int wave = tid>>6, lane = tid&63, l15 = lane&15, quad = lane>>4;
  int m0 = blockIdx.y*128, n0 = blockIdx.x*128;
  int wm = (wave>>1)*64, wn = (wave&1)*64;
  int srow = tid>>1, scw = (tid&1)*16;
  const bf16* Ap = A + (size_t)(m0+srow)*K + scw;
  const bf16* Wp = W + (size_t)(n0+srow)*K + scw;
  floatx4 zero = {0.f,0.f,0.f,0.f};
  floatx4 acc[4][4];
  #pragma unroll
  for (int i=0;i<4;i++)
    #pragma unroll
    for (int j=0;j<4;j++) acc[i][j] = zero;

  for (int k0 = 0; k0 < K; k0 += 32) {
    float4 a0 = *(const float4*)Ap, a1 = *(const float4*)(Ap+8);
    float4 w0 = *(const float4*)Wp, w1 = *(const float4*)(Wp+8);
    Ap += 32; Wp += 32;
    __syncthreads();
    *(float4*)&As[srow][scw]   = a0; *(float4*)&As[srow][scw+8] = a1;
    *(float4*)&Bs[srow][scw]   = w0; *(float4*)&Bs[srow][scw+8] = w1;
    __syncthreads();
    short8 af[4], bfv[4];
    #pragma unroll
    for (int mi=0;mi<4;mi++) af[mi]  = *(const short8*)&As[wm+mi*16+l15][quad*8];
    #pragma unroll
    for (int ni=0;ni<4;ni++) bfv[ni] = *(const short8*)&Bs[wn+ni*16+l15][quad*8];
    #pragma unroll
    for (int mi=0;mi<4;mi++)
      #pragma unroll
      for (int ni=0;ni<4;ni++)
        acc[mi][ni] = __builtin_amdgcn_mfma_f32_16x16x32_bf16(af[mi], bfv[ni], acc[mi][ni], 0,0,0);
  }
  #pragma unroll
  for (int mi=0;mi<4;mi++){
    #pragma unroll
    for (int ni=0;ni<4;ni++){
      int n = n0 + wn + ni*16 + l15;
      float bb = (b1 ? b1[n] : 0.f) + (b2 ? b2[n] : 0.f);
      #pragma unroll
      for (int r=0;r<4;r++){
        int m = m0 + wm + mi*16 + quad*4 + r;
        float v = acc[mi][ni][r] + bb;
        if (relu) v = fmaxf(v, 0.f);
        storev(&Cv[(size_t)m*N + n], v);
      }
    }
  }
}

// ---------- naive GEMM for fc3 (N=48) ----------
__global__ __launch_bounds__(256) void gemm_nt_small(
  const bf16* __restrict__ A, const float* __restrict__ W,
  const float* __restrict__ b1, float* __restrict__ Cv, int M, int N, int K)
{
  __shared__ float As[8][128];
  __shared__ float Ws[8][128];
  int tid = threadIdx.x;
  int tx = tid & 15, ty = tid >> 4;
  int m0 = blockIdx.y * 128, n0 = blockIdx.x * 128;
  int sr = tid >> 1;
  int sk = (tid & 1) * 4;
  const bf16* Ap = A + (size_t)(m0 + sr) * K + sk;
  bool wok = (n0 + sr) < N;
  const float* Wp = W + (size_t)(wok ? (n0 + sr) : 0) * K + sk;
  float acc[8][8] = {};
  for (int k0 = 0; k0 < K; k0 += 8) {
    float av[4], wv[4];
    load4f(Ap, av);
    if (wok) { float4 t = *(const float4*)Wp; wv[0]=t.x; wv[1]=t.y; wv[2]=t.z; wv[3]=t.w; }
    else { wv[0]=wv[1]=wv[2]=wv[3]=0.f; }
    Ap += 8; Wp += 8;
    __syncthreads();
    As[sk+0][sr]=av[0]; As[sk+1][sr]=av[1]; As[sk+2][sr]=av[2]; As[sk+3][sr]=av[3];
    Ws[sk+0][sr]=wv[0]; Ws[sk+1][sr]=wv[1]; Ws[sk+2][sr]=wv[2]; Ws[sk+3][sr]=wv[3];
    __syncthreads();
    #pragma unroll
    for (int kk = 0; kk < 8; kk++) {
      float a[8], w[8];
      *(float4*)&a[0] = *(const float4*)&As[kk][ty*8];
      *(float4*)&a[4] = *(const float4*)&As[kk][ty*8+4];
      *(float4*)&w[0] = *(const float4*)&Ws[kk][tx*8];
      *(float4*)&w[4] = *(const float4*)&Ws[kk][tx*8+4];
      #pragma unroll
      for (int i=0;i<8;i++)
        #pragma unroll
        for (int j=0;j<8;j++) acc[i][j] += a[i]*w[j];
    }
  }
  #pragma unroll
  for (int i=0;i<8;i++){
    int m = m0 + ty*8 + i;
    #pragma unroll
    for (int j=0;j<8;j++){
      int n = n0 + tx*8 + j;
      if (n < N) Cv[(size_t)m*N + n] = acc[i][j] + b1[n];
    }
  }
}

// ---------- persistent BiLSTM layer: 64 blocks = dir(2) x jslice(32 of 16 units) ----------
// Whole 256-step recurrence in ONE kernel. Weights in LDS (loaded once), c-state in
// registers, h ping-pong in global, device-scope slot barrier between steps.
__global__ __launch_bounds__(256,1) void lstm_persist(
  const bf16* __restrict__ preF, const bf16* __restrict__ preB,
  const bf16* __restrict__ WF, const bf16* __restrict__ WB,   // Whh bf16 2048x512 row-major
  bf16* __restrict__ hbuf,          // [2 pingpong][2 dir][64][512]
  bf16* __restrict__ xout,          // [64][256][1024]
  const float* __restrict__ bnscale, const float* __restrict__ bnshift,
  int* __restrict__ slots)          // [64], zeroed before launch
{
  __shared__ bf16 wlds[64][520];    // 64 gate-rows x 512 k, +8 pad (2-way banks = free)
  int blk = blockIdx.x;
  int dir = blk & 1;
  int js  = blk >> 1;               // 0..31
  int j0  = js * 16;
  const bf16* pre = dir ? preB : preF;
  const bf16* W   = dir ? WB : WF;
  int colOff = dir ? Hz : 0;
  int tid = threadIdx.x;
  int wave = tid >> 6, lane = tid & 63, l15 = lane & 15, quad = lane >> 4;

  // --- load weight slice once: lds row n = g*16+idx <-> Whh row g*512 + j0 + idx ---
  for (int chunk = tid; chunk < 64*64; chunk += 256) {
    int n = chunk >> 6, col = (chunk & 63) * 8;
    int g = n >> 4, idx = n & 15;
    *(float4*)&wlds[n][col] = *(const float4*)(W + ((size_t)(g*512 + j0 + idx))*Hz + col);
  }
  __syncthreads();

  int bb = wave*16 + quad*4;        // batch base for this lane's accumulator rows
  int j  = j0 + l15;                // this lane's hidden unit
  float sc = bnscale ? bnscale[colOff + j] : 1.f;
  float sh = bnshift ? bnshift[colOff + j] : 0.f;
  int useBN = bnscale ? 1 : 0;
  float c[4] = {0.f,0.f,0.f,0.f};

  for (int t = 0; t < Sz; t++) {
    int tcur = dir ? (Sz-1-t) : t;
    floatx4 zero = {0.f,0.f,0.f,0.f};
    floatx4 acc[4] = {zero, zero, zero, zero};

    // prefetch pre-activations for this step (4 batches x 4 gates)
    float pg[4][4];
    #pragma unroll
    for (int r=0;r<4;r++){
      const bf16* pb = pre + ((size_t)(bb+r)*Sz + tcur)*FH;
      #pragma unroll
      for (int g=0;g<4;g++) pg[g][r] = b2f(pb[g*512 + j]);
    }

    if (t > 0) {
      const bf16* hprev = hbuf + ((size_t)((t&1)*2 + dir))*Bz*Hz;
      short8 af[16];
      #pragma unroll
      for (int ks=0;ks<16;ks++)
        af[ks] = *(const short8*)(hprev + (size_t)(wave*16 + l15)*Hz + ks*32 + quad*8);
      #pragma unroll
      for (int g=0; g<4; g++)
        #pragma unroll
        for (int ks=0; ks<16; ks++){
          short8 bfv = *(const short8*)&wlds[g*16 + l15][ks*32 + quad*8];
          acc[g] = __builtin_amdgcn_mfma_f32_16x16x32_bf16(af[ks], bfv, acc[g], 0,0,0);
        }
    }

    bf16* hnext = hbuf + ((size_t)(((t+1)&1)*2 + dir))*Bz*Hz;
    #pragma unroll
    for (int r=0;r<4;r++){
      int b = bb + r;
      float gi = acc[0][r] + pg[0][r];
      float gf = acc[1][r] + pg[1][r];
      float gg = acc[2][r] + pg[2][r];
      float go = acc[3][r] + pg[3][r];
      float cv = fsig(gf)*c[r] + fsig(gi)*ftanh(gg);
      float h  = fsig(go)*ftanh(cv);
      c[r] = cv;
      hnext[(size_t)b*Hz + j] = __float2bfloat16(h);
      float xv = useBN ? (h*sc + sh) : h;
      xout[((size_t)b*Sz + tcur)*OH + colOff + j] = __float2bfloat16(xv);
    }

    // --- device-scope step barrier (skip after last step) ---
    if (t < Sz-1) {
      __syncthreads();                    // drains vmcnt: all h writes complete to L2
      if (tid == 0)
        __hip_atomic_store(&slots[blk], t+1, __ATOMIC_RELEASE, __HIP_MEMORY_SCOPE_AGENT);
      if (tid < 64) {
        while (!__all(__hip_atomic_load(&slots[lane], __ATOMIC_ACQUIRE, __HIP_MEMORY_SCOPE_AGENT) > t)) {}
      }
      __syncthreads();
    }
  }
}

// ---------- CRF ----------
__global__ __launch_bounds__(64) void crf_k(const float* __restrict__ em, const int* __restrict__ tags,
  const float* __restrict__ start, const float* __restrict__ endv, const float* __restrict__ trans,
  float* __restrict__ result)
{
  __shared__ float tr[Tz*Tz];
  __shared__ float alpha[2][Tz];
  int b = blockIdx.x, tid = threadIdx.x;
  for (int i = tid; i < Tz*Tz; i += 64) tr[i] = trans[i];
  float np = 0.f;
  for (int t = tid; t < Sz; t += 64) {
    int tg = tags[b*Sz + t];
    np += em[((size_t)b*Sz + t)*Tz + tg];
    if (t+1 < Sz) np += trans[tg*Tz + tags[b*Sz + t + 1]];
  }
  #pragma unroll
  for (int off = 32; off; off >>= 1) np += __shfl_down(np, off);
  float num = 0.f;
  if (tid == 0) num = np + start[tags[b*Sz]] + endv[tags[b*Sz + Sz-1]];
  if (tid < Tz) alpha[0][tid] = start[tid] + em[((size_t)b*Sz)*Tz + tid];
  __syncthreads();
  int cur = 0;
  for (int t = 1; t < Sz; t++) {
    if (tid < Tz) {
      float m = -1e30f;
      for (int i = 0; i < Tz; i++) m = fmaxf(m, alpha[cur][i] + tr[i*Tz + tid]);
      float sum = 0.f;
      for (int i = 0; i < Tz; i++) sum += expf(alpha[cur][i] + tr[i*Tz + tid] - m);
      alpha[1-cur][tid] = m + logf(sum) + em[((size_t)b*Sz + t)*Tz + tid];
    }
    cur ^= 1;
    __syncthreads();
  }
  float a = (tid < Tz) ? alpha[cur][tid] + endv[tid] : -1e30f;
  float m = a;
  #pragma unroll
  for (int off = 32; off; off >>= 1) m = fmaxf(m, __shfl_down(m, off));
  m = __shfl(m, 0);
  float e = (tid < Tz) ? expf(a - m) : 0.f;
  #pragma unroll
  for (int off = 32; off; off >>= 1) e += __shfl_down(e, off);
  if (tid == 0) result[b] = num - (m + logf(e));
}

__global__ __launch_bounds__(64) void finalize_k(const float* __restrict__ result, float* __restrict__ outp)
{
  float v = result[threadIdx.x];
  #pragma unroll
  for (int off = 32; off; off >>= 1) v += __shfl_down(v, off);
  if (threadIdx.x == 0) outp[0] = -(v * (1.f/64.f));
}

extern "C" void kernel_launch(void* const* d_in, const int* in_sizes, int n_in,
                              void* d_out, int out_size, void* d_ws, size_t ws_size,
                              hipStream_t stream)
{
  (void)in_sizes; (void)n_in; (void)out_size; (void)ws_size;
  const float* inputs = (const float*)d_in[0];
  const int*   tags   = (const int*)d_in[1];
  const float* Wih[2][2] = {{(const float*)d_in[2],  (const float*)d_in[6]},
                            {(const float*)d_in[10], (const float*)d_in[14]}};
  const float* Whh[2][2] = {{(const float*)d_in[3],  (const float*)d_in[7]},
                            {(const float*)d_in[11], (const float*)d_in[15]}};
  const float* bih[2][2] = {{(const float*)d_in[4],  (const float*)d_in[8]},
                            {(const float*)d_in[12], (const float*)d_in[16]}};
  const float* bhh[2][2] = {{(const float*)d_in[5],  (const float*)d_in[9]},
                            {(const float*)d_in[13], (const float*)d_in[17]}};
  const float* bn_gamma = (const float*)d_in[18];
  const float* bn_beta  = (const float*)d_in[19];
  const float* bn_mean  = (const float*)d_in[20];
  const float* bn_var   = (const float*)d_in[21];
  const float* fc1_w = (const float*)d_in[22];
  const float* fc1_b = (const float*)d_in[23];
  const float* fc2_w = (const float*)d_in[24];
  const float* fc2_b = (const float*)d_in[25];
  const float* fc3_w = (const float*)d_in[26];
  const float* fc3_b = (const float*)d_in[27];
  const float* crf_start = (const float*)d_in[28];
  const float* crf_end   = (const float*)d_in[29];
  const float* crf_trans = (const float*)d_in[30];

  const size_t M = (size_t)Bz*Sz;   // 16384
  char* p = (char*)d_ws;
  auto alloc = [&](size_t bytes) { char* r = p; p += (bytes + 255) & ~(size_t)255; return r; };
  bf16*  preF  = (bf16*) alloc(M*FH*sizeof(bf16));            // 64 MB
  bf16*  preB  = (bf16*) alloc(M*FH*sizeof(bf16));            // 64 MB
  bf16*  xbuf  = (bf16*) alloc(M*OH*sizeof(bf16));            // 32 MB
  bf16*  inbf  = (bf16*) alloc(M*Dz*sizeof(bf16));            // 8 MB (em overlays later)
  bf16*  Wih0A = (bf16*) alloc((size_t)FH*Dz*sizeof(bf16));   // 1 MB
  bf16*  Wih0B = (bf16*) alloc((size_t)FH*Dz*sizeof(bf16));
  bf16*  Wih1A = (bf16*) alloc((size_t)FH*OH*sizeof(bf16));   // 4 MB
  bf16*  Wih1B = (bf16*) alloc((size_t)FH*OH*sizeof(bf16));
  bf16*  Whh0A = (bf16*) alloc((size_t)FH*Hz*sizeof(bf16));   // 2 MB
  bf16*  Whh0B = (bf16*) alloc((size_t)FH*Hz*sizeof(bf16));
  bf16*  Whh1A = (bf16*) alloc((size_t)FH*Hz*sizeof(bf16));
  bf16*  Whh1B = (bf16*) alloc((size_t)FH*Hz*sizeof(bf16));
  bf16*  fc1wb = (bf16*) alloc((size_t)Hz*OH*sizeof(bf16));   // 1 MB
  bf16*  fc2wb = (bf16*) alloc((size_t)256*Hz*sizeof(bf16));  // 0.25 MB
  bf16*  hbuf  = (bf16*) alloc(4*(size_t)Bz*Hz*sizeof(bf16)); // 256 KB (pp x dir)
  int*   slots = (int*)  alloc(128*sizeof(int));              // 2 layers x 64
  float* bnscale = (float*)alloc(OH*sizeof(float));
  float* bnshift = (float*)alloc(OH*sizeof(float));
  float* result  = (float*)alloc(Bz*sizeof(float));
  float* em   = (float*)inbf;                                 // overlay (3 MB <= 8 MB)
  bf16* fc1o = (bf16*)preF;                                   // overlays after recurrence
  bf16* fc2o = (bf16*)preB;

  dim3 tb(256);
  auto cast = [&](const float* src, bf16* dst, size_t n){
    castf2b<<<(n/4 + 255)/256, tb, 0, stream>>>(src, dst, (int)n);
  };

  // barrier slots must be zero (ws is poisoned 0xAA before every run)
  hipMemsetAsync(slots, 0, 128*sizeof(int), stream);
  // upfront casts (all independent of compute)
  cast(inputs, inbf, M*Dz);
  cast(Wih[0][0], Wih0A, (size_t)FH*Dz);
  cast(Wih[0][1], Wih0B, (size_t)FH*Dz);
  cast(Wih[1][0], Wih1A, (size_t)FH*OH);
  cast(Wih[1][1], Wih1B, (size_t)FH*OH);
  cast(Whh[0][0], Whh0A, (size_t)FH*Hz);
  cast(Whh[0][1], Whh0B, (size_t)FH*Hz);
  cast(Whh[1][0], Whh1A, (size_t)FH*Hz);
  cast(Whh[1][1], Whh1B, (size_t)FH*Hz);
  cast(fc1_w, fc1wb, (size_t)Hz*OH);
  cast(fc2_w, fc2wb, (size_t)256*Hz);
  bnprep_k<<<OH/256, tb, 0, stream>>>(bn_gamma, bn_beta, bn_mean, bn_var, bnscale, bnshift);

  // ---- layer 0 ----
  gemm_mfma<bf16><<<dim3(FH/128, M/128), tb, 0, stream>>>(inbf, Wih0A, bih[0][0], bhh[0][0], preF, M, FH, Dz, 0);
  gemm_mfma<bf16><<<dim3(FH/128, M/128), tb, 0, stream>>>(inbf, Wih0B, bih[0][1], bhh[0][1], preB, M, FH, Dz, 0);
  lstm_persist<<<64, tb, 0, stream>>>(preF, preB, Whh0A, Whh0B, hbuf, xbuf, nullptr, nullptr, slots);
  // ---- layer 1 ----
  gemm_mfma<bf16><<<dim3(FH/128, M/128), tb, 0, stream>>>(xbuf, Wih1A, bih[1][0], bhh[1][0], preF, M, FH, OH, 0);
  gemm_mfma<bf16><<<dim3(FH/128, M/128), tb, 0, stream>>>(xbuf, Wih1B, bih[1][1], bhh[1][1], preB, M, FH, OH, 0);
  lstm_persist<<<64, tb, 0, stream>>>(preF, preB, Whh1A, Whh1B, hbuf, xbuf, bnscale, bnshift, slots + 64);
  // ---- head ----
  gemm_mfma<bf16><<<dim3(Hz/128, M/128), tb, 0, stream>>>(xbuf, fc1wb, fc1_b, nullptr, fc1o, M, Hz, OH, 1);
  gemm_mfma<bf16><<<dim3(256/128, M/128), tb, 0, stream>>>(fc1o, fc2wb, fc2_b, nullptr, fc2o, M, 256, Hz, 1);
  gemm_nt_small<<<dim3(1, M/128), tb, 0, stream>>>(fc2o, fc3_w, fc3_b, em, M, Tz, 256);
  crf_k<<<Bz, 64, 0, stream>>>(em, tags, crf_start, crf_end, crf_trans, result);
  finalize_k<<<1, 64, 0, stream>>>(result, (float*)d_out);
}